// Round 1
// baseline (372.796 us; speedup 1.0000x reference)
//
#include <hip/hip_runtime.h>
#include <cfloat>
#include <math.h>

#define BB 4
#define NR 180
#define CC 512
#define HH 48
#define WW 48
#define FF (CC*4)      // 2048
#define OO 64
#define EPSV 1e-5f

// ---------------- Kernel 1: transpose [B,C,H,W] -> [B,H*W,C], zero stats ----
__global__ __launch_bounds__(256) void k_transpose(const float* __restrict__ feat,
                                                   float* __restrict__ featT,
                                                   float* __restrict__ sum1,
                                                   float* __restrict__ sq1) {
    __shared__ float tile[32][33];
    const int S = HH * WW;                 // 2304
    int b  = blockIdx.z;
    int s0 = blockIdx.x * 32;              // gridDim.x = 72
    int c0 = blockIdx.y * 32;              // gridDim.y = 16
    int tx = threadIdx.x, ty = threadIdx.y;

    const float* src = feat + (size_t)b * CC * S;
    float* dst       = featT + (size_t)b * S * CC;

    #pragma unroll
    for (int k = 0; k < 4; k++) {
        int c = c0 + ty + k * 8;
        tile[ty + k * 8][tx] = src[(size_t)c * S + (s0 + tx)];
    }
    __syncthreads();
    #pragma unroll
    for (int k = 0; k < 4; k++) {
        int s = s0 + ty + k * 8;
        dst[(size_t)s * CC + (c0 + tx)] = tile[tx][ty + k * 8];
    }

    if (blockIdx.x == 0 && blockIdx.y == 0 && blockIdx.z == 0) {
        int t = ty * 32 + tx;
        if (t < NR) { sum1[t] = 0.f; sq1[t] = 0.f; }
    }
}

// ---------------- Kernel 2: ROI 2x2 adaptive max pool + ReLU + BN1 partials -
__global__ __launch_bounds__(256) void k_pool(const float* __restrict__ featT,
                                              const float* __restrict__ rois,
                                              float* __restrict__ px,
                                              float* __restrict__ sum1,
                                              float* __restrict__ sq1) {
    int blk = blockIdx.x;
    int b = blk & 3;
    int n = blk >> 2;
    int tid = threadIdx.x;

    const float* roi = rois + ((size_t)b * NR + n) * 4;
    float r0f = roi[0] * 0.25f;
    float r1f = roi[1] * 0.25f;
    float r2f = roi[2] * 0.25f;
    float r3f = roi[3] * 0.25f;
    int r0 = (int)r0f;            // trunc (coords nonneg)
    int r1 = (int)r1f;
    int r2 = (int)ceilf(r2f);
    int r3 = (int)ceilf(r3f);
    int hs = r2 - r0 + 1;
    int wsz = r3 - r1 + 1;
    int eh0 = (hs + 1) >> 1, sh1 = hs >> 1;
    int ew0 = (wsz + 1) >> 1, sw1 = wsz >> 1;

    int c2 = tid * 2;             // this thread handles channels c2, c2+1
    float ma0 = -FLT_MAX, ma1 = -FLT_MAX, ma2 = -FLT_MAX, ma3 = -FLT_MAX;
    float mb0 = -FLT_MAX, mb1 = -FLT_MAX, mb2 = -FLT_MAX, mb3 = -FLT_MAX;

    for (int h = 0; h < hs; h++) {
        int hh = r0 + h;
        bool i0 = (h < eh0), i1 = (h >= sh1);
        const float* fp = featT + ((size_t)((b * HH + hh) * WW + r1)) * CC + c2;
        float cm0a = -FLT_MAX, cm1a = -FLT_MAX;
        float cm0b = -FLT_MAX, cm1b = -FLT_MAX;
        for (int w = 0; w < wsz; w++) {
            float2 v = *(const float2*)fp;
            fp += CC;
            bool j0 = (w < ew0), j1 = (w >= sw1);
            if (j0) { cm0a = fmaxf(cm0a, v.x); cm0b = fmaxf(cm0b, v.y); }
            if (j1) { cm1a = fmaxf(cm1a, v.x); cm1b = fmaxf(cm1b, v.y); }
        }
        if (i0) { ma0 = fmaxf(ma0, cm0a); ma1 = fmaxf(ma1, cm1a);
                  mb0 = fmaxf(mb0, cm0b); mb1 = fmaxf(mb1, cm1b); }
        if (i1) { ma2 = fmaxf(ma2, cm0a); ma3 = fmaxf(ma3, cm1a);
                  mb2 = fmaxf(mb2, cm0b); mb3 = fmaxf(mb3, cm1b); }
    }

    // ReLU
    ma0 = fmaxf(ma0, 0.f); ma1 = fmaxf(ma1, 0.f); ma2 = fmaxf(ma2, 0.f); ma3 = fmaxf(ma3, 0.f);
    mb0 = fmaxf(mb0, 0.f); mb1 = fmaxf(mb1, 0.f); mb2 = fmaxf(mb2, 0.f); mb3 = fmaxf(mb3, 0.f);

    // store: f = c*4 + oi*2 + oj  (torch flatten order)
    float* op = px + ((size_t)(b * NR + n)) * FF + (size_t)c2 * 4;
    *(float4*)(op)     = make_float4(ma0, ma1, ma2, ma3);
    *(float4*)(op + 4) = make_float4(mb0, mb1, mb2, mb3);

    // BN1 partial stats over this block's 2048 values
    float s  = ma0 + ma1 + ma2 + ma3 + mb0 + mb1 + mb2 + mb3;
    float sq = ma0*ma0 + ma1*ma1 + ma2*ma2 + ma3*ma3
             + mb0*mb0 + mb1*mb1 + mb2*mb2 + mb3*mb3;
    for (int off = 32; off; off >>= 1) {
        s  += __shfl_down(s, off);
        sq += __shfl_down(sq, off);
    }
    __shared__ float ps[4], pq[4];
    int wv = tid >> 6, ln = tid & 63;
    if (ln == 0) { ps[wv] = s; pq[wv] = sq; }
    __syncthreads();
    if (tid == 0) {
        atomicAdd(&sum1[n], ps[0] + ps[1] + ps[2] + ps[3]);
        atomicAdd(&sq1[n],  pq[0] + pq[1] + pq[2] + pq[3]);
    }
}

// ---------------- Kernel 3: BN1-normalize + GEMM + bias + BN2 ---------------
__global__ __launch_bounds__(256) void k_gemm(const float* __restrict__ px,
                                              const float* __restrict__ W1,
                                              const float* __restrict__ bl1,
                                              const float* __restrict__ g1,
                                              const float* __restrict__ b1,
                                              const float* __restrict__ g2,
                                              const float* __restrict__ b2,
                                              const float* __restrict__ sum1,
                                              const float* __restrict__ sq1,
                                              float* __restrict__ out) {
    __shared__ float xs[BB][FF];          // 32 KB, BN1-normalized inputs
    __shared__ float rs[4], rq[4];
    int n = blockIdx.x;
    int tid = threadIdx.x;
    int b = tid >> 6;                     // wave b: all lanes same b -> LDS broadcast
    int o = tid & 63;

    const float inv1 = 1.f / (float)(BB * FF);
    float mean = sum1[n] * inv1;
    float var  = sq1[n] * inv1 - mean * mean;
    float a  = g1[n] * rsqrtf(var + EPSV);
    float cc = b1[n] - mean * a;

    for (int bb = 0; bb < BB; bb++) {
        const float4* srcv = (const float4*)(px + ((size_t)(bb * NR + n)) * FF);
        float4* dstv = (float4*)&xs[bb][0];
        for (int i = tid; i < FF / 4; i += 256) {
            float4 v = srcv[i];
            v.x = a * v.x + cc; v.y = a * v.y + cc;
            v.z = a * v.z + cc; v.w = a * v.w + cc;
            dstv[i] = v;
        }
    }
    __syncthreads();

    const float4* wr = (const float4*)(W1 + (size_t)o * FF);
    const float4* xv = (const float4*)&xs[b][0];
    float acc0 = 0.f, acc1 = 0.f, acc2 = 0.f, acc3 = 0.f;
    #pragma unroll 8
    for (int k = 0; k < FF / 4; k++) {
        float4 w4 = wr[k];
        float4 x4 = xv[k];
        acc0 += w4.x * x4.x;
        acc1 += w4.y * x4.y;
        acc2 += w4.z * x4.z;
        acc3 += w4.w * x4.w;
    }
    float y = acc0 + acc1 + acc2 + acc3 + bl1[o];

    // BN2 over the 256 (b,o) values of this n
    float s = y, sq = y * y;
    for (int off = 32; off; off >>= 1) {
        s  += __shfl_down(s, off);
        sq += __shfl_down(sq, off);
    }
    int wv = tid >> 6, ln = tid & 63;
    if (ln == 0) { rs[wv] = s; rq[wv] = sq; }
    __syncthreads();
    float sm  = rs[0] + rs[1] + rs[2] + rs[3];
    float sqm = rq[0] + rq[1] + rq[2] + rq[3];
    const float inv2 = 1.f / 256.f;
    float mean2 = sm * inv2;
    float var2  = sqm * inv2 - mean2 * mean2;
    float r2s = rsqrtf(var2 + EPSV);
    out[((size_t)b * NR + n) * OO + o] = (y - mean2) * r2s * g2[n] + b2[n];
}

extern "C" void kernel_launch(void* const* d_in, const int* in_sizes, int n_in,
                              void* d_out, int out_size, void* d_ws, size_t ws_size,
                              hipStream_t stream) {
    const float* feat = (const float*)d_in[0];   // [4,512,48,48]
    const float* rois = (const float*)d_in[1];   // [4,180,4]
    const float* g1   = (const float*)d_in[2];   // [180]
    const float* b1   = (const float*)d_in[3];   // [180]
    const float* W1   = (const float*)d_in[4];   // [64,2048]
    const float* bl1  = (const float*)d_in[5];   // [64]
    const float* g2   = (const float*)d_in[6];   // [180]
    const float* b2   = (const float*)d_in[7];   // [180]
    float* out = (float*)d_out;

    float* ws    = (float*)d_ws;
    float* featT = ws;                                    // 4*2304*512 = 4718592
    float* px    = ws + 4718592;                          // 4*180*2048 = 1474560
    float* sum1  = px + 1474560;
    float* sq1   = sum1 + NR;

    dim3 tb(32, 8);
    k_transpose<<<dim3(72, 16, 4), tb, 0, stream>>>(feat, featT, sum1, sq1);
    k_pool<<<BB * NR, 256, 0, stream>>>(featT, rois, px, sum1, sq1);
    k_gemm<<<NR, 256, 0, stream>>>(px, W1, bl1, g1, b1, g2, b2, sum1, sq1, out);
}

// Round 2
// 146.097 us; speedup vs baseline: 2.5517x; 2.5517x over previous
//
#include <hip/hip_runtime.h>
#include <cfloat>
#include <math.h>

#define BB 4
#define NR 180
#define CC 512
#define HH 48
#define WW 48
#define FF (CC*4)      // 2048
#define OO 64
#define EPSV 1e-5f

// ---- ws layout (float offsets) ----
#define FEATT_SZ (BB*HH*WW*CC)       // 4,718,592
#define W1T_SZ   (OO*FF)             // 131,072
#define PX_SZ    (BB*NR*FF)          // 1,474,560

__device__ __forceinline__ float4 max4(float4 a, float4 b) {
    return make_float4(fmaxf(a.x,b.x), fmaxf(a.y,b.y), fmaxf(a.z,b.z), fmaxf(a.w,b.w));
}

// ---------------- Kernel 1: transposes + zero stats -------------------------
// z<4 : feat [B,C,H,W] -> featT [B,H*W,C]   (b = z)
// z==4: W1 [64,2048] -> W1T [2048,64]
__global__ __launch_bounds__(256) void k_prep(const float* __restrict__ feat,
                                              const float* __restrict__ W1,
                                              float* __restrict__ featT,
                                              float* __restrict__ W1T,
                                              float* __restrict__ sum1,
                                              float* __restrict__ sq1) {
    __shared__ float tile[32][33];
    int tx = threadIdx.x, ty = threadIdx.y;
    int z = blockIdx.z;

    if (z < 4) {
        const int S = HH * WW;                 // 2304
        int b  = z;
        int s0 = blockIdx.x * 32;              // gridDim.x = 72
        int c0 = blockIdx.y * 32;              // gridDim.y = 16
        const float* src = feat + (size_t)b * CC * S;
        float* dst       = featT + (size_t)b * S * CC;
        #pragma unroll
        for (int k = 0; k < 4; k++) {
            int c = c0 + ty + k * 8;
            tile[ty + k * 8][tx] = src[(size_t)c * S + (s0 + tx)];
        }
        __syncthreads();
        #pragma unroll
        for (int k = 0; k < 4; k++) {
            int s = s0 + ty + k * 8;
            dst[(size_t)s * CC + (c0 + tx)] = tile[tx][ty + k * 8];
        }
        if (blockIdx.x == 0 && blockIdx.y == 0 && z == 0) {
            int t = ty * 32 + tx;
            if (t < NR) { sum1[t] = 0.f; sq1[t] = 0.f; }
        }
    } else {
        int idx = blockIdx.y * 72 + blockIdx.x;    // 0..1151
        if (idx >= 128) return;                    // need 64 ktiles x 2 otiles
        int kt = idx >> 1, ot = idx & 1;
        int o0 = ot * 32, k0 = kt * 32;
        #pragma unroll
        for (int k = 0; k < 4; k++) {
            int o = o0 + ty + k * 8;
            tile[ty + k * 8][tx] = W1[(size_t)o * FF + (k0 + tx)];
        }
        __syncthreads();
        #pragma unroll
        for (int k = 0; k < 4; k++) {
            int kk = k0 + ty + k * 8;
            W1T[(size_t)kk * OO + (o0 + tx)] = tile[tx][ty + k * 8];
        }
    }
}

// ---------------- Kernel 2: ROI 2x2 adaptive max pool + ReLU + BN1 stats ----
// grid 720 (b,n), block 1024 = 8 rowgroups x 128 ch-threads (4 ch each, float4)
__global__ __launch_bounds__(1024) void k_pool(const float* __restrict__ featT,
                                               const float* __restrict__ rois,
                                               float* __restrict__ px,
                                               float* __restrict__ sum1,
                                               float* __restrict__ sq1) {
    __shared__ float lds[8][FF];              // 64 KB
    __shared__ float part_s[16], part_q[16];
    int blk = blockIdx.x;
    int b = blk & 3, n = blk >> 2;
    int tid = threadIdx.x;
    int g  = tid >> 7;                        // rowgroup 0..7
    int c4 = (tid & 127) << 2;                // channels c4..c4+3

    const float* roi = rois + ((size_t)b * NR + n) * 4;
    int r0 = (int)(roi[0] * 0.25f);           // trunc, coords nonneg
    int r1 = (int)(roi[1] * 0.25f);
    int r2 = (int)ceilf(roi[2] * 0.25f);
    int r3 = (int)ceilf(roi[3] * 0.25f);
    int hs  = r2 - r0 + 1;
    int wsz = r3 - r1 + 1;
    int eh0 = (hs + 1) >> 1, sh1 = hs >> 1;
    int ew0 = (wsz + 1) >> 1, sw1 = wsz >> 1;

    const float NEG = -FLT_MAX;
    float4 q00 = make_float4(NEG,NEG,NEG,NEG);
    float4 q01 = q00, q10 = q00, q11 = q00;

    for (int h = g; h < hs; h += 8) {
        const float* rp = featT + ((size_t)((b * HH + r0 + h) * WW + r1)) * CC + c4;
        float4 cm0 = make_float4(NEG,NEG,NEG,NEG);
        float4 cm1 = cm0;
        for (int w = 0; w < ew0; w++)              // quadrant col 0
            cm0 = max4(cm0, *(const float4*)(rp + (size_t)w * CC));
        for (int w = sw1; w < wsz; w++)            // quadrant col 1
            cm1 = max4(cm1, *(const float4*)(rp + (size_t)w * CC));
        if (h <  eh0) { q00 = max4(q00, cm0); q01 = max4(q01, cm1); }
        if (h >= sh1) { q10 = max4(q10, cm0); q11 = max4(q11, cm1); }
    }

    // per-channel f = c*4 + oi*2 + oj  -> 16 consecutive floats per thread
    int fb = c4 << 2;
    *(float4*)&lds[g][fb]      = make_float4(q00.x, q01.x, q10.x, q11.x);
    *(float4*)&lds[g][fb + 4]  = make_float4(q00.y, q01.y, q10.y, q11.y);
    *(float4*)&lds[g][fb + 8]  = make_float4(q00.z, q01.z, q10.z, q11.z);
    *(float4*)&lds[g][fb + 12] = make_float4(q00.w, q01.w, q10.w, q11.w);
    __syncthreads();

    // combine 8 rowgroups: thread handles f = 2*tid, 2*tid+1
    int f0 = tid << 1;
    float2 m = *(const float2*)&lds[0][f0];
    #pragma unroll
    for (int gg = 1; gg < 8; gg++) {
        float2 v = *(const float2*)&lds[gg][f0];
        m.x = fmaxf(m.x, v.x); m.y = fmaxf(m.y, v.y);
    }
    m.x = fmaxf(m.x, 0.f); m.y = fmaxf(m.y, 0.f);      // ReLU
    *(float2*)(px + ((size_t)(b * NR + n)) * FF + f0) = m;

    // BN1 partial stats (2048 values per block)
    float s  = m.x + m.y;
    float sq = m.x * m.x + m.y * m.y;
    for (int off = 32; off; off >>= 1) {
        s  += __shfl_down(s, off);
        sq += __shfl_down(sq, off);
    }
    if ((tid & 63) == 0) { part_s[tid >> 6] = s; part_q[tid >> 6] = sq; }
    __syncthreads();
    if (tid == 0) {
        float ts = 0.f, tq = 0.f;
        #pragma unroll
        for (int i = 0; i < 16; i++) { ts += part_s[i]; tq += part_q[i]; }
        atomicAdd(&sum1[n], ts);
        atomicAdd(&sq1[n], tq);
    }
}

// ---------------- Kernel 3: GEMM (BN1 folded) + bias + BN2 ------------------
// grid 180 (n), block 1024 = 16 kchunks x 64 o-lanes; each thread does 4 b's
__global__ __launch_bounds__(1024) void k_gemm(const float* __restrict__ px,
                                               const float* __restrict__ W1T,
                                               const float* __restrict__ bl1,
                                               const float* __restrict__ g1,
                                               const float* __restrict__ b1,
                                               const float* __restrict__ g2,
                                               const float* __restrict__ b2,
                                               const float* __restrict__ sum1,
                                               const float* __restrict__ sq1,
                                               float* __restrict__ out) {
    __shared__ float xs[BB][FF];          // 32 KB raw pooled x
    __shared__ float pd[16][BB][OO];      // 16 KB dot partials
    __shared__ float pw[16][OO];          // 4 KB wsum partials
    __shared__ float sm2[4], sq2[4];
    int n = blockIdx.x;
    int tid = threadIdx.x;
    int s = tid >> 6;                     // kchunk, wave-uniform
    int o = tid & 63;                     // lane

    // stage raw px into LDS (coalesced float4)
    for (int i = tid; i < BB * FF / 4; i += 1024) {
        int bb = i >> 9, idx = i & 511;
        ((float4*)&xs[bb][0])[idx] =
            ((const float4*)(px + ((size_t)(bb * NR + n)) * FF))[idx];
    }
    __syncthreads();

    int k0 = s << 7;                      // 128-k chunk
    float a0 = 0.f, a1 = 0.f, a2 = 0.f, a3 = 0.f, wsum = 0.f;
    #pragma unroll 8
    for (int k = k0; k < k0 + 128; k++) {
        float w = W1T[(size_t)k * OO + o];          // coalesced over lanes
        wsum += w;
        a0 += w * xs[0][k];                         // wave-uniform broadcasts
        a1 += w * xs[1][k];
        a2 += w * xs[2][k];
        a3 += w * xs[3][k];
    }
    pd[s][0][o] = a0; pd[s][1][o] = a1; pd[s][2][o] = a2; pd[s][3][o] = a3;
    pw[s][o] = wsum;
    __syncthreads();

    float y = 0.f;
    int b = tid >> 6;                     // for tid<256: wave = b, lane = o
    if (tid < 256) {
        float dot = 0.f, ws = 0.f;
        #pragma unroll
        for (int ss = 0; ss < 16; ss++) { dot += pd[ss][b][o]; ws += pw[ss][o]; }
        const float inv1 = 1.f / (float)(BB * FF);
        float mean = sum1[n] * inv1;
        float var  = sq1[n] * inv1 - mean * mean;
        float a  = g1[n] * rsqrtf(var + EPSV);
        float cc = b1[n] - mean * a;
        y = a * dot + cc * ws + bl1[o];
        // BN2 partials: each wave (= one b) reduces its 64 y's
        float rs = y, rq = y * y;
        for (int off = 32; off; off >>= 1) {
            rs += __shfl_down(rs, off);
            rq += __shfl_down(rq, off);
        }
        if (o == 0) { sm2[b] = rs; sq2[b] = rq; }
    }
    __syncthreads();
    if (tid < 256) {
        float sm  = sm2[0] + sm2[1] + sm2[2] + sm2[3];
        float sqm = sq2[0] + sq2[1] + sq2[2] + sq2[3];
        const float inv2 = 1.f / 256.f;
        float mean2 = sm * inv2;
        float var2  = sqm * inv2 - mean2 * mean2;
        float r2s = rsqrtf(var2 + EPSV);
        out[((size_t)b * NR + n) * OO + o] = (y - mean2) * r2s * g2[n] + b2[n];
    }
}

extern "C" void kernel_launch(void* const* d_in, const int* in_sizes, int n_in,
                              void* d_out, int out_size, void* d_ws, size_t ws_size,
                              hipStream_t stream) {
    const float* feat = (const float*)d_in[0];   // [4,512,48,48]
    const float* rois = (const float*)d_in[1];   // [4,180,4]
    const float* g1   = (const float*)d_in[2];
    const float* b1   = (const float*)d_in[3];
    const float* W1   = (const float*)d_in[4];   // [64,2048]
    const float* bl1  = (const float*)d_in[5];
    const float* g2   = (const float*)d_in[6];
    const float* b2   = (const float*)d_in[7];
    float* out = (float*)d_out;

    float* ws    = (float*)d_ws;
    float* featT = ws;
    float* W1T   = featT + FEATT_SZ;
    float* px    = W1T + W1T_SZ;
    float* sum1  = px + PX_SZ;
    float* sq1   = sum1 + NR;

    dim3 tb(32, 8);
    k_prep<<<dim3(72, 16, 5), tb, 0, stream>>>(feat, W1, featT, W1T, sum1, sq1);
    k_pool<<<BB * NR, 1024, 0, stream>>>(featT, rois, px, sum1, sq1);
    k_gemm<<<NR, 1024, 0, stream>>>(px, W1T, bl1, g1, b1, g2, b2, sum1, sq1, out);
}

// Round 4
// 144.051 us; speedup vs baseline: 2.5879x; 1.0142x over previous
//
#include <hip/hip_runtime.h>
#include <hip/hip_bf16.h>
#include <cfloat>
#include <math.h>

#define BB 4
#define NR 180
#define CC 512
#define HH 48
#define WW 48
#define FF (CC*4)      // 2048
#define OO 64
#define EPSV 1e-5f
#define NCH 4          // row-chunks per ROI

// ---- ws layout ----
// featB : BB*HH*WW*CC ushort  = 4,718,592 us (9.4 MB)
// W1T   : OO*FF float         = 131,072 f  (0.5 MB)
// pp    : BB*NR*NCH*FF ushort = 5,898,240 us (11.8 MB)  layout [b*NR+n][ch][f]

__device__ __forceinline__ void unpk(unsigned u, float& lo, float& hi) {
    lo = __uint_as_float(u << 16);
    hi = __uint_as_float(u & 0xffff0000u);
}

// ---------------- Kernel 1: transposes --------------------------------------
// z<4 : feat [B,C,H,W] fp32 -> featB [B,H*W,C] bf16
// z==4: W1 [64,2048] -> W1T [2048,64] fp32  (x<8 only)
__global__ __launch_bounds__(256) void k_prep(const float* __restrict__ feat,
                                              const float* __restrict__ W1,
                                              __hip_bfloat16* __restrict__ featB,
                                              float* __restrict__ W1T) {
    __shared__ float tile[32][33];
    int tx = threadIdx.x, ty = threadIdx.y;
    int z = blockIdx.z;

    if (z < 4) {
        const int S = HH * WW;                 // 2304
        int b  = z;
        int s0 = blockIdx.x * 32;              // gridDim.x = 72
        int c0 = blockIdx.y * 32;              // gridDim.y = 16
        const float* src = feat + (size_t)b * CC * S;
        __hip_bfloat16* dst = featB + (size_t)b * S * CC;
        #pragma unroll
        for (int k = 0; k < 4; k++) {
            int c = c0 + ty + k * 8;
            tile[ty + k * 8][tx] = src[(size_t)c * S + (s0 + tx)];
        }
        __syncthreads();
        #pragma unroll
        for (int k = 0; k < 4; k++) {
            int s = s0 + ty + k * 8;
            dst[(size_t)s * CC + (c0 + tx)] = __float2bfloat16(tile[tx][ty + k * 8]);
        }
    } else {
        if (blockIdx.x >= 8) return;               // 8*16 = 128 tile-blocks
        int kt = blockIdx.y * 8 + blockIdx.x;      // 0..127
        int k0 = (kt >> 1) * 32, o0 = (kt & 1) * 32;
        #pragma unroll
        for (int k = 0; k < 4; k++) {
            int o = o0 + ty + k * 8;
            tile[ty + k * 8][tx] = W1[(size_t)o * FF + (k0 + tx)];
        }
        __syncthreads();
        #pragma unroll
        for (int k = 0; k < 4; k++) {
            int kk = k0 + ty + k * 8;
            W1T[(size_t)kk * OO + (o0 + tx)] = tile[tx][ty + k * 8];
        }
    }
}

// ---------------- Kernel 2: ROI 2x2 adaptive max pool, chunked --------------
// grid (NCH, 720), block 256 = 4 rowgroups x 64 ch-threads (8 bf16 ch each)
// chunk ch + rowgroup g handle region-rows L = ch*4+g + 16*i  (<=3 rows/thread)
__global__ __launch_bounds__(256) void k_pool(const ushort* __restrict__ featB,
                                              const float* __restrict__ rois,
                                              ushort* __restrict__ pp) {
    __shared__ float lds[4][FF];              // 32 KB
    int ch = blockIdx.x;
    int bn = blockIdx.y;
    int b = bn & 3, n = bn >> 2;
    int tid = threadIdx.x;
    int g  = tid >> 6;
    int c8 = (tid & 63) << 3;

    const float* roi = rois + ((size_t)b * NR + n) * 4;
    int r0 = (int)(roi[0] * 0.25f);
    int r1 = (int)(roi[1] * 0.25f);
    int r2 = (int)ceilf(roi[2] * 0.25f);
    int r3 = (int)ceilf(roi[3] * 0.25f);
    int hs  = r2 - r0 + 1;
    int wsz = r3 - r1 + 1;
    int eh0 = (hs + 1) >> 1, sh1 = hs >> 1;
    int ew0 = (wsz + 1) >> 1, sw1 = wsz >> 1;

    const float NEG = -FLT_MAX;
    float q00[8], q01[8], q10[8], q11[8];
    #pragma unroll
    for (int j = 0; j < 8; j++) { q00[j]=NEG; q01[j]=NEG; q10[j]=NEG; q11[j]=NEG; }

    for (int L = ch * 4 + g; L < hs; L += 16) {
        const ushort* rp = featB + ((size_t)((b * HH + r0 + L) * WW + r1)) * CC + c8;
        float cm0[8], cm1[8];
        #pragma unroll
        for (int j = 0; j < 8; j++) { cm0[j]=NEG; cm1[j]=NEG; }
        for (int w = 0; w < ew0; w++) {
            uint4 u = *(const uint4*)(rp + (size_t)w * CC);
            float a,bb2;
            unpk(u.x,a,bb2); cm0[0]=fmaxf(cm0[0],a); cm0[1]=fmaxf(cm0[1],bb2);
            unpk(u.y,a,bb2); cm0[2]=fmaxf(cm0[2],a); cm0[3]=fmaxf(cm0[3],bb2);
            unpk(u.z,a,bb2); cm0[4]=fmaxf(cm0[4],a); cm0[5]=fmaxf(cm0[5],bb2);
            unpk(u.w,a,bb2); cm0[6]=fmaxf(cm0[6],a); cm0[7]=fmaxf(cm0[7],bb2);
        }
        for (int w = sw1; w < wsz; w++) {
            uint4 u = *(const uint4*)(rp + (size_t)w * CC);
            float a,bb2;
            unpk(u.x,a,bb2); cm1[0]=fmaxf(cm1[0],a); cm1[1]=fmaxf(cm1[1],bb2);
            unpk(u.y,a,bb2); cm1[2]=fmaxf(cm1[2],a); cm1[3]=fmaxf(cm1[3],bb2);
            unpk(u.z,a,bb2); cm1[4]=fmaxf(cm1[4],a); cm1[5]=fmaxf(cm1[5],bb2);
            unpk(u.w,a,bb2); cm1[6]=fmaxf(cm1[6],a); cm1[7]=fmaxf(cm1[7],bb2);
        }
        if (L < eh0) {
            #pragma unroll
            for (int j = 0; j < 8; j++) { q00[j]=fmaxf(q00[j],cm0[j]); q01[j]=fmaxf(q01[j],cm1[j]); }
        }
        if (L >= sh1) {
            #pragma unroll
            for (int j = 0; j < 8; j++) { q10[j]=fmaxf(q10[j],cm0[j]); q11[j]=fmaxf(q11[j],cm1[j]); }
        }
    }

    // f = c*4 + oi*2 + oj
    int fb = c8 << 2;
    #pragma unroll
    for (int j = 0; j < 8; j++)
        *(float4*)&lds[g][fb + j * 4] = make_float4(q00[j], q01[j], q10[j], q11[j]);
    __syncthreads();

    // combine rowgroups; pack 8 f-values to bf16 (exact: inputs were bf16)
    int f0 = tid << 3;
    unsigned w0 = 0, w1 = 0, w2 = 0, w3 = 0;
    {
        float m[8];
        #pragma unroll
        for (int j = 0; j < 8; j++) {
            float v = lds[0][f0 + j];
            v = fmaxf(v, lds[1][f0 + j]);
            v = fmaxf(v, lds[2][f0 + j]);
            v = fmaxf(v, lds[3][f0 + j]);
            m[j] = v;
        }
        w0 = (__float_as_uint(m[0]) >> 16) | (__float_as_uint(m[1]) & 0xffff0000u);
        w1 = (__float_as_uint(m[2]) >> 16) | (__float_as_uint(m[3]) & 0xffff0000u);
        w2 = (__float_as_uint(m[4]) >> 16) | (__float_as_uint(m[5]) & 0xffff0000u);
        w3 = (__float_as_uint(m[6]) >> 16) | (__float_as_uint(m[7]) & 0xffff0000u);
    }
    uint4 outv = make_uint4(w0, w1, w2, w3);
    // layout [b*NR+n][ch][f]  (R3 bug: used bn = n*4+b here while k_gemm read b*NR+n)
    *(uint4*)(pp + (((size_t)(b * NR + n) * NCH + ch) * FF + f0)) = outv;
}

// ---------------- Kernel 3: reduce chunks + ReLU + BN1 + GEMM + BN2 ---------
// grid 180, block 1024 = 16 kchunk-waves x 64 o-lanes
__global__ __launch_bounds__(1024) void k_gemm(const ushort* __restrict__ pp,
                                               const float* __restrict__ W1T,
                                               const float* __restrict__ bl1,
                                               const float* __restrict__ g1,
                                               const float* __restrict__ b1,
                                               const float* __restrict__ g2,
                                               const float* __restrict__ b2,
                                               float* __restrict__ out) {
    __shared__ float xs[BB][FF];          // 32 KB
    __shared__ float pd[16][BB][OO];      // 16 KB
    __shared__ float pw[16][OO];          // 4 KB
    __shared__ float part_s[16], part_q[16];
    __shared__ float sm2[4], sq2[4];
    int n = blockIdx.x;
    int tid = threadIdx.x;

    // stage: reduce 4 chunk-partials, ReLU, accumulate BN1 stats
    float s_acc = 0.f, q_acc = 0.f;
    #pragma unroll
    for (int k2 = 0; k2 < 2; k2++) {
        int gi = tid + (k2 << 10);            // 0..2047
        int bb = gi >> 9;
        int idx = gi & 511;                   // which uint2 (4 bf16)
        const unsigned* base = (const unsigned*)(pp + ((size_t)(bb * NR + n)) * NCH * FF);
        float v0 = -FLT_MAX, v1 = -FLT_MAX, v2 = -FLT_MAX, v3 = -FLT_MAX;
        #pragma unroll
        for (int c = 0; c < NCH; c++) {
            uint2 u = *(const uint2*)(base + c * (FF / 2) + idx * 2);
            float a, b_;
            unpk(u.x, a, b_); v0 = fmaxf(v0, a); v1 = fmaxf(v1, b_);
            unpk(u.y, a, b_); v2 = fmaxf(v2, a); v3 = fmaxf(v3, b_);
        }
        v0 = fmaxf(v0, 0.f); v1 = fmaxf(v1, 0.f); v2 = fmaxf(v2, 0.f); v3 = fmaxf(v3, 0.f);
        *(float4*)&xs[bb][idx << 2] = make_float4(v0, v1, v2, v3);
        s_acc += v0 + v1 + v2 + v3;
        q_acc += v0*v0 + v1*v1 + v2*v2 + v3*v3;
    }
    for (int off = 32; off; off >>= 1) {
        s_acc += __shfl_down(s_acc, off);
        q_acc += __shfl_down(q_acc, off);
    }
    if ((tid & 63) == 0) { part_s[tid >> 6] = s_acc; part_q[tid >> 6] = q_acc; }
    __syncthreads();
    float ts = 0.f, tq = 0.f;
    #pragma unroll
    for (int i = 0; i < 16; i++) { ts += part_s[i]; tq += part_q[i]; }
    const float inv1 = 1.f / (float)(BB * FF);
    float mean = ts * inv1;
    float var  = tq * inv1 - mean * mean;
    float a1n  = g1[n] * rsqrtf(var + EPSV);
    float c1n  = b1[n] - mean * a1n;

    int sc = tid >> 6;                    // kchunk
    int o  = tid & 63;
    int k0 = sc << 7;
    float a0 = 0.f, a1 = 0.f, a2 = 0.f, a3 = 0.f, wsum = 0.f;
    #pragma unroll 8
    for (int k = k0; k < k0 + 128; k++) {
        float w = W1T[(size_t)k * OO + o];
        wsum += w;
        a0 += w * xs[0][k];
        a1 += w * xs[1][k];
        a2 += w * xs[2][k];
        a3 += w * xs[3][k];
    }
    pd[sc][0][o] = a0; pd[sc][1][o] = a1; pd[sc][2][o] = a2; pd[sc][3][o] = a3;
    pw[sc][o] = wsum;
    __syncthreads();

    float y = 0.f;
    int b = tid >> 6;
    if (tid < 256) {
        float dot = 0.f, wsm = 0.f;
        #pragma unroll
        for (int ss = 0; ss < 16; ss++) { dot += pd[ss][b][o]; wsm += pw[ss][o]; }
        y = a1n * dot + c1n * wsm + bl1[o];
        float rs = y, rq = y * y;
        for (int off = 32; off; off >>= 1) {
            rs += __shfl_down(rs, off);
            rq += __shfl_down(rq, off);
        }
        if (o == 0) { sm2[b] = rs; sq2[b] = rq; }
    }
    __syncthreads();
    if (tid < 256) {
        float sm  = sm2[0] + sm2[1] + sm2[2] + sm2[3];
        float sqm = sq2[0] + sq2[1] + sq2[2] + sq2[3];
        const float inv2 = 1.f / 256.f;
        float mean2 = sm * inv2;
        float var2  = sqm * inv2 - mean2 * mean2;
        float r2s = rsqrtf(var2 + EPSV);
        out[((size_t)b * NR + n) * OO + o] = (y - mean2) * r2s * g2[n] + b2[n];
    }
}

extern "C" void kernel_launch(void* const* d_in, const int* in_sizes, int n_in,
                              void* d_out, int out_size, void* d_ws, size_t ws_size,
                              hipStream_t stream) {
    const float* feat = (const float*)d_in[0];
    const float* rois = (const float*)d_in[1];
    const float* g1   = (const float*)d_in[2];
    const float* b1   = (const float*)d_in[3];
    const float* W1   = (const float*)d_in[4];
    const float* bl1  = (const float*)d_in[5];
    const float* g2   = (const float*)d_in[6];
    const float* b2   = (const float*)d_in[7];
    float* out = (float*)d_out;

    ushort* featB = (ushort*)d_ws;                    // 4,718,592 ushort
    float*  W1T   = (float*)(featB + (size_t)BB*HH*WW*CC);
    ushort* pp    = (ushort*)(W1T + (size_t)OO*FF);   // 5,898,240 ushort

    dim3 tb(32, 8);
    k_prep<<<dim3(72, 16, 5), tb, 0, stream>>>(feat, W1, (__hip_bfloat16*)featB, W1T);
    k_pool<<<dim3(NCH, BB * NR), 256, 0, stream>>>(featB, rois, pp);
    k_gemm<<<NR, 1024, 0, stream>>>(pp, W1T, bl1, g1, b1, g2, b2, out);
}

// Round 5
// 122.221 us; speedup vs baseline: 3.0502x; 1.1786x over previous
//
#include <hip/hip_runtime.h>
#include <hip/hip_bf16.h>
#include <cfloat>
#include <math.h>

#define BB 4
#define NR 180
#define CC 512
#define HH 48
#define WW 48
#define FF (CC*4)      // 2048
#define OO 64
#define EPSV 1e-5f
#define NCH 4

// ---- ws layout ----
// featB : BB*HH*WW*CC ushort  = 4,718,592 us
// W1T4  : [512][64][4] float  = 131,072 f   (W1T4[k>>2][o][k&3] = W1[o][k])
// pp    : BB*NR*NCH*FF ushort               layout [b*NR+n][ch][f], pre-ReLU'd

__device__ __forceinline__ void unpk(unsigned u, float& lo, float& hi) {
    lo = __uint_as_float(u << 16);
    hi = __uint_as_float(u & 0xffff0000u);
}
__device__ __forceinline__ unsigned pk(float lo, float hi) {
    return (__float_as_uint(lo) >> 16) | (__float_as_uint(hi) & 0xffff0000u);
}
__device__ __forceinline__ void acc8(float* cm, uint4 u) {
    float a, b;
    unpk(u.x, a, b); cm[0] = fmaxf(cm[0], a); cm[1] = fmaxf(cm[1], b);
    unpk(u.y, a, b); cm[2] = fmaxf(cm[2], a); cm[3] = fmaxf(cm[3], b);
    unpk(u.z, a, b); cm[4] = fmaxf(cm[4], a); cm[5] = fmaxf(cm[5], b);
    unpk(u.w, a, b); cm[6] = fmaxf(cm[6], a); cm[7] = fmaxf(cm[7], b);
}

// ---------------- Kernel 1: transposes --------------------------------------
// z<4 : feat [B,C,H,W] fp32 -> featB [B,H*W,C] bf16   (float4 reads, uint2 writes)
// z==4: W1 [64,2048] -> W1T4 [512][64][4] fp32
__global__ __launch_bounds__(256) void k_prep(const float* __restrict__ feat,
                                              const float* __restrict__ W1,
                                              __hip_bfloat16* __restrict__ featB,
                                              float* __restrict__ W1T4) {
    __shared__ float tile[32][33];
    int t = threadIdx.x;
    int z = blockIdx.z;

    if (z < 4) {
        const int S = HH * WW;                 // 2304 (multiple of 32)
        int b  = z;
        int s0 = blockIdx.x * 32;              // gridDim.x = 72
        int c0 = blockIdx.y * 32;              // gridDim.y = 16
        const float* src = feat + (size_t)b * CC * S;
        ushort* dst = (ushort*)featB + (size_t)b * S * CC;

        int cl = t >> 3;                       // 0..31
        int sx = (t & 7) << 2;                 // 0,4,..,28
        float4 v = *(const float4*)(src + (size_t)(c0 + cl) * S + s0 + sx);
        tile[cl][sx] = v.x; tile[cl][sx+1] = v.y; tile[cl][sx+2] = v.z; tile[cl][sx+3] = v.w;
        __syncthreads();

        int sl = t >> 3;                       // 0..31
        int c4 = (t & 7) << 2;                 // 0,4,..,28
        unsigned u0 = pk(tile[c4][sl],   tile[c4+1][sl]);
        unsigned u1 = pk(tile[c4+2][sl], tile[c4+3][sl]);
        *(uint2*)(dst + (size_t)(s0 + sl) * CC + c0 + c4) = make_uint2(u0, u1);
    } else {
        if (blockIdx.x >= 8) return;               // 8*16 = 128 tiles
        int kt = blockIdx.y * 8 + blockIdx.x;      // 0..127
        int k0 = (kt >> 1) * 32, o0 = (kt & 1) * 32;
        int tx = t & 31, ty = t >> 5;              // 32 x 8
        #pragma unroll
        for (int k = 0; k < 4; k++) {
            int row = ty + k * 8;
            tile[row][tx] = W1[(size_t)(o0 + row) * FF + (k0 + tx)];
        }
        __syncthreads();
        #pragma unroll
        for (int k = 0; k < 4; k++) {
            int row = ty + k * 8;                  // k-index within tile
            int kk = k0 + row;
            int o  = o0 + tx;
            W1T4[(size_t)(kk >> 2) * 256 + o * 4 + (kk & 3)] = tile[tx][row];
        }
    }
}

// ---------------- Kernel 2: ROI 2x2 adaptive max pool, chunked --------------
// grid (NCH, 720), block 256 = 4 rowgroups(g) x 64 ch-threads (8 bf16 ch)
// w-loops unrolled x4 with batched loads for MLP; LDS reduce in packed bf16.
__global__ __launch_bounds__(256, 6) void k_pool(const ushort* __restrict__ featB,
                                                 const float* __restrict__ rois,
                                                 ushort* __restrict__ pp) {
    __shared__ unsigned lu[4][16][64];        // 16 KB, conflict-free (lane stride 4B)
    int ch = blockIdx.x;
    int bn = blockIdx.y;
    int b = bn & 3, n = bn >> 2;
    int tid = threadIdx.x;
    int g  = tid >> 6;
    int c  = tid & 63;
    int c8 = c << 3;

    const float* roi = rois + ((size_t)b * NR + n) * 4;
    int r0 = (int)(roi[0] * 0.25f);
    int r1 = (int)(roi[1] * 0.25f);
    int r2 = (int)ceilf(roi[2] * 0.25f);
    int r3 = (int)ceilf(roi[3] * 0.25f);
    int hs  = r2 - r0 + 1;
    int wsz = r3 - r1 + 1;
    int eh0 = (hs + 1) >> 1, sh1 = hs >> 1;
    int ew0 = (wsz + 1) >> 1, sw1 = wsz >> 1;

    const float NEG = -FLT_MAX;
    float q00[8], q01[8], q10[8], q11[8];
    #pragma unroll
    for (int j = 0; j < 8; j++) { q00[j]=NEG; q01[j]=NEG; q10[j]=NEG; q11[j]=NEG; }

    for (int L = ch * 4 + g; L < hs; L += 16) {
        const ushort* rp = featB + ((size_t)((b * HH + r0 + L) * WW + r1)) * CC + c8;
        float cm0[8], cm1[8];
        #pragma unroll
        for (int j = 0; j < 8; j++) { cm0[j]=NEG; cm1[j]=NEG; }

        int w = 0;
        for (; w + 4 <= ew0; w += 4) {
            const ushort* p = rp + (size_t)w * CC;
            uint4 u0 = *(const uint4*)(p);
            uint4 u1 = *(const uint4*)(p + CC);
            uint4 u2 = *(const uint4*)(p + 2 * CC);
            uint4 u3 = *(const uint4*)(p + 3 * CC);
            acc8(cm0, u0); acc8(cm0, u1); acc8(cm0, u2); acc8(cm0, u3);
        }
        for (; w < ew0; w++) acc8(cm0, *(const uint4*)(rp + (size_t)w * CC));

        w = sw1;
        for (; w + 4 <= wsz; w += 4) {
            const ushort* p = rp + (size_t)w * CC;
            uint4 u0 = *(const uint4*)(p);
            uint4 u1 = *(const uint4*)(p + CC);
            uint4 u2 = *(const uint4*)(p + 2 * CC);
            uint4 u3 = *(const uint4*)(p + 3 * CC);
            acc8(cm1, u0); acc8(cm1, u1); acc8(cm1, u2); acc8(cm1, u3);
        }
        for (; w < wsz; w++) acc8(cm1, *(const uint4*)(rp + (size_t)w * CC));

        if (L < eh0) {
            #pragma unroll
            for (int j = 0; j < 8; j++) { q00[j]=fmaxf(q00[j],cm0[j]); q01[j]=fmaxf(q01[j],cm1[j]); }
        }
        if (L >= sh1) {
            #pragma unroll
            for (int j = 0; j < 8; j++) { q10[j]=fmaxf(q10[j],cm0[j]); q11[j]=fmaxf(q11[j],cm1[j]); }
        }
    }

    // pack quadrants to bf16 pairs: j = jc*2 + oi; (lo,hi) = (oj0, oj1)
    #pragma unroll
    for (int jc = 0; jc < 8; jc++) {
        lu[g][jc * 2 + 0][c] = pk(q00[jc], q01[jc]);
        lu[g][jc * 2 + 1][c] = pk(q10[jc], q11[jc]);
    }
    __syncthreads();

    // cross-rowgroup reduce + ReLU; thread -> (c2, j0..j0+3) = 4 consecutive uints
    int c2 = tid & 63, j0 = (tid >> 6) * 4;
    unsigned ou[4];
    #pragma unroll
    for (int jj = 0; jj < 4; jj++) {
        int j = j0 + jj;
        float lo = NEG, hi = NEG;
        #pragma unroll
        for (int gg = 0; gg < 4; gg++) {
            float a, bb2; unpk(lu[gg][j][c2], a, bb2);
            lo = fmaxf(lo, a); hi = fmaxf(hi, bb2);
        }
        lo = fmaxf(lo, 0.f); hi = fmaxf(hi, 0.f);
        ou[jj] = pk(lo, hi);
    }
    unsigned* dst = (unsigned*)(pp + ((size_t)(b * NR + n) * NCH + ch) * FF);
    *(uint4*)(dst + c2 * 16 + j0) = make_uint4(ou[0], ou[1], ou[2], ou[3]);
}

// ---------------- Kernel 3: reduce chunks + ReLU + BN1 + GEMM + BN2 ---------
// grid 180, block 1024 = 16 kchunk-waves x 64 o-lanes
__global__ __launch_bounds__(1024) void k_gemm(const ushort* __restrict__ pp,
                                               const float* __restrict__ W1T4,
                                               const float* __restrict__ bl1,
                                               const float* __restrict__ g1,
                                               const float* __restrict__ b1,
                                               const float* __restrict__ g2,
                                               const float* __restrict__ b2,
                                               float* __restrict__ out) {
    __shared__ float xs[BB][FF];          // 32 KB
    __shared__ float pd[16][BB][OO];      // 16 KB
    __shared__ float pw[16][OO];          // 4 KB
    __shared__ float part_s[16], part_q[16];
    __shared__ float sm2[4], sq2[4];
    int n = blockIdx.x;
    int tid = threadIdx.x;

    float s_acc = 0.f, q_acc = 0.f;
    #pragma unroll
    for (int k2 = 0; k2 < 2; k2++) {
        int gi = tid + (k2 << 10);            // 0..2047
        int bb = gi >> 9;
        int idx = gi & 511;
        const unsigned* base = (const unsigned*)(pp + ((size_t)(bb * NR + n)) * NCH * FF);
        float v0 = -FLT_MAX, v1 = -FLT_MAX, v2 = -FLT_MAX, v3 = -FLT_MAX;
        #pragma unroll
        for (int cch = 0; cch < NCH; cch++) {
            uint2 u = *(const uint2*)(base + cch * (FF / 2) + idx * 2);
            float a, b_;
            unpk(u.x, a, b_); v0 = fmaxf(v0, a); v1 = fmaxf(v1, b_);
            unpk(u.y, a, b_); v2 = fmaxf(v2, a); v3 = fmaxf(v3, b_);
        }
        v0 = fmaxf(v0, 0.f); v1 = fmaxf(v1, 0.f); v2 = fmaxf(v2, 0.f); v3 = fmaxf(v3, 0.f);
        *(float4*)&xs[bb][idx << 2] = make_float4(v0, v1, v2, v3);
        s_acc += v0 + v1 + v2 + v3;
        q_acc += v0*v0 + v1*v1 + v2*v2 + v3*v3;
    }
    for (int off = 32; off; off >>= 1) {
        s_acc += __shfl_down(s_acc, off);
        q_acc += __shfl_down(q_acc, off);
    }
    if ((tid & 63) == 0) { part_s[tid >> 6] = s_acc; part_q[tid >> 6] = q_acc; }
    __syncthreads();
    float ts = 0.f, tq = 0.f;
    #pragma unroll
    for (int i = 0; i < 16; i++) { ts += part_s[i]; tq += part_q[i]; }
    const float inv1 = 1.f / (float)(BB * FF);
    float mean = ts * inv1;
    float var  = tq * inv1 - mean * mean;
    float a1n  = g1[n] * rsqrtf(var + EPSV);
    float c1n  = b1[n] - mean * a1n;

    int sc = tid >> 6;
    int o  = tid & 63;
    int k4a = sc << 5;                     // 32 float4-k groups per chunk
    float a0 = 0.f, a1 = 0.f, a2 = 0.f, a3 = 0.f, wsum = 0.f;
    #pragma unroll 4
    for (int k4 = k4a; k4 < k4a + 32; k4++) {
        float4 w4 = *(const float4*)(W1T4 + (size_t)k4 * 256 + o * 4);  // coalesced 16B/lane
        float4 x0 = *(const float4*)&xs[0][k4 << 2];                    // uniform broadcast
        float4 x1 = *(const float4*)&xs[1][k4 << 2];
        float4 x2 = *(const float4*)&xs[2][k4 << 2];
        float4 x3 = *(const float4*)&xs[3][k4 << 2];
        wsum += w4.x + w4.y + w4.z + w4.w;
        a0 += w4.x*x0.x + w4.y*x0.y + w4.z*x0.z + w4.w*x0.w;
        a1 += w4.x*x1.x + w4.y*x1.y + w4.z*x1.z + w4.w*x1.w;
        a2 += w4.x*x2.x + w4.y*x2.y + w4.z*x2.z + w4.w*x2.w;
        a3 += w4.x*x3.x + w4.y*x3.y + w4.z*x3.z + w4.w*x3.w;
    }
    pd[sc][0][o] = a0; pd[sc][1][o] = a1; pd[sc][2][o] = a2; pd[sc][3][o] = a3;
    pw[sc][o] = wsum;
    __syncthreads();

    float y = 0.f;
    int b = tid >> 6;
    if (tid < 256) {
        float dot = 0.f, wsm = 0.f;
        #pragma unroll
        for (int ss = 0; ss < 16; ss++) { dot += pd[ss][b][o]; wsm += pw[ss][o]; }
        y = a1n * dot + c1n * wsm + bl1[o];
        float rs = y, rq = y * y;
        for (int off = 32; off; off >>= 1) {
            rs += __shfl_down(rs, off);
            rq += __shfl_down(rq, off);
        }
        if (o == 0) { sm2[b] = rs; sq2[b] = rq; }
    }
    __syncthreads();
    if (tid < 256) {
        float sm  = sm2[0] + sm2[1] + sm2[2] + sm2[3];
        float sqm = sq2[0] + sq2[1] + sq2[2] + sq2[3];
        const float inv2 = 1.f / 256.f;
        float mean2 = sm * inv2;
        float var2  = sqm * inv2 - mean2 * mean2;
        float r2s = rsqrtf(var2 + EPSV);
        out[((size_t)b * NR + n) * OO + o] = (y - mean2) * r2s * g2[n] + b2[n];
    }
}

extern "C" void kernel_launch(void* const* d_in, const int* in_sizes, int n_in,
                              void* d_out, int out_size, void* d_ws, size_t ws_size,
                              hipStream_t stream) {
    const float* feat = (const float*)d_in[0];
    const float* rois = (const float*)d_in[1];
    const float* g1   = (const float*)d_in[2];
    const float* b1   = (const float*)d_in[3];
    const float* W1   = (const float*)d_in[4];
    const float* bl1  = (const float*)d_in[5];
    const float* g2   = (const float*)d_in[6];
    const float* b2   = (const float*)d_in[7];
    float* out = (float*)d_out;

    ushort* featB = (ushort*)d_ws;                    // 4,718,592 ushort
    float*  W1T4  = (float*)(featB + (size_t)BB*HH*WW*CC);
    ushort* pp    = (ushort*)(W1T4 + (size_t)OO*FF);

    k_prep<<<dim3(72, 16, 5), 256, 0, stream>>>(feat, W1, (__hip_bfloat16*)featB, W1T4);
    k_pool<<<dim3(NCH, BB * NR), 256, 0, stream>>>(featB, rois, pp);
    k_gemm<<<NR, 1024, 0, stream>>>(pp, W1T4, bl1, g1, b1, g2, b2, out);
}

// Round 6
// 117.379 us; speedup vs baseline: 3.1760x; 1.0412x over previous
//
#include <hip/hip_runtime.h>
#include <hip/hip_bf16.h>
#include <cfloat>
#include <math.h>

#define BB 4
#define NR 180
#define CC 512
#define HH 48
#define WW 48
#define FF (CC*4)      // 2048
#define OO 64
#define EPSV 1e-5f
#define NCH 4

// ---- ws layout ----
// featB : BB*HW*CC ushort (MAPPED u16 domain)
// W1T4  : [512][64][4] float   (W1T4[k>>2][o][k&3] = W1[o][k])
// pp    : [b*NR+n][ch][f] ushort (MAPPED domain, ReLU'd)
//
// order-preserving map bf16 -> u16:  neg ? ~u : u|0x8000.  max/ReLU become
// unsigned integer max (v_pk_max_u16), 4 VALU per uint4 vs 24 for unpack+fmax.

typedef unsigned short us2 __attribute__((ext_vector_type(2)));

__device__ __forceinline__ unsigned pmax(unsigned a, unsigned b) {
    return __builtin_bit_cast(unsigned, __builtin_elementwise_max(
        __builtin_bit_cast(us2, a), __builtin_bit_cast(us2, b)));
}
__device__ __forceinline__ uint4 pmax4(uint4 a, uint4 b) {
    return make_uint4(pmax(a.x,b.x), pmax(a.y,b.y), pmax(a.z,b.z), pmax(a.w,b.w));
}
__device__ __forceinline__ unsigned mapb(float f) {      // float -> mapped u16
    unsigned fu = __float_as_uint(f);
    unsigned u = fu >> 16;
    return (fu >> 31) ? (~u & 0xFFFFu) : (u | 0x8000u);
}
__device__ __forceinline__ void unmap2(unsigned m, float& lo, float& hi) {
    unsigned t = ((~m) >> 15) & 0x00010001u;             // 1 where orig negative
    unsigned u = m ^ (0x80008000u ^ (t * 0x7FFFu));      // per-lane: ^0x8000 / ^0xFFFF
    lo = __uint_as_float(u << 16);
    hi = __uint_as_float(u & 0xffff0000u);
}

// ---------------- Kernel 1: transposes --------------------------------------
__global__ __launch_bounds__(256) void k_prep(const float* __restrict__ feat,
                                              const float* __restrict__ W1,
                                              ushort* __restrict__ featB,
                                              float* __restrict__ W1T4) {
    __shared__ float tile[32][33];
    int t = threadIdx.x;
    int z = blockIdx.z;

    if (z < 4) {
        const int S = HH * WW;                 // 2304
        int b  = z;
        int s0 = blockIdx.x * 32;              // gridDim.x = 72
        int c0 = blockIdx.y * 32;              // gridDim.y = 16
        const float* src = feat + (size_t)b * CC * S;
        ushort* dst = featB + (size_t)b * S * CC;

        int cl = t >> 3;
        int sx = (t & 7) << 2;
        float4 v = *(const float4*)(src + (size_t)(c0 + cl) * S + s0 + sx);
        tile[cl][sx] = v.x; tile[cl][sx+1] = v.y; tile[cl][sx+2] = v.z; tile[cl][sx+3] = v.w;
        __syncthreads();

        int sl = t >> 3;
        int c4 = (t & 7) << 2;
        unsigned u0 = mapb(tile[c4][sl])   | (mapb(tile[c4+1][sl]) << 16);
        unsigned u1 = mapb(tile[c4+2][sl]) | (mapb(tile[c4+3][sl]) << 16);
        *(uint2*)(dst + (size_t)(s0 + sl) * CC + c0 + c4) = make_uint2(u0, u1);
    } else {
        if (blockIdx.x >= 8) return;
        int kt = blockIdx.y * 8 + blockIdx.x;      // 0..127
        int k0 = (kt >> 1) * 32, o0 = (kt & 1) * 32;
        int tx = t & 31, ty = t >> 5;
        #pragma unroll
        for (int k = 0; k < 4; k++) {
            int row = ty + k * 8;
            tile[row][tx] = W1[(size_t)(o0 + row) * FF + (k0 + tx)];
        }
        __syncthreads();
        #pragma unroll
        for (int k = 0; k < 4; k++) {
            int row = ty + k * 8;
            int kk = k0 + row;
            int o  = o0 + tx;
            W1T4[(size_t)(kk >> 2) * 256 + o * 4 + (kk & 3)] = tile[tx][row];
        }
    }
}

// ---------------- Kernel 2: ROI 2x2 adaptive max pool, mapped-int domain ----
// grid (NCH, 720), block 256 = 4 rowgroups(g) x 64 ch-threads (8 ch via uint4)
__global__ __launch_bounds__(256, 6) void k_pool(const ushort* __restrict__ featB,
                                                 const float* __restrict__ rois,
                                                 ushort* __restrict__ pp) {
    __shared__ unsigned lu[4][16][64];        // 16 KB, conflict-free
    int ch = blockIdx.x;
    int bn = blockIdx.y;
    int b = bn & 3, n = bn >> 2;
    int tid = threadIdx.x;
    int g = tid >> 6, c = tid & 63;

    const float* roi = rois + ((size_t)b * NR + n) * 4;
    int r0 = (int)(roi[0] * 0.25f);
    int r1 = (int)(roi[1] * 0.25f);
    int r2 = (int)ceilf(roi[2] * 0.25f);
    int r3 = (int)ceilf(roi[3] * 0.25f);
    int hs  = r2 - r0 + 1;
    int wsz = r3 - r1 + 1;
    int eh0 = (hs + 1) >> 1, sh1 = hs >> 1;
    int ew0 = (wsz + 1) >> 1, sw1 = wsz >> 1;

    const uint4 Z = make_uint4(0,0,0,0);      // 0 < any mapped value's floor
    uint4 q00 = Z, q01 = Z, q10 = Z, q11 = Z;

    for (int L = ch * 4 + g; L < hs; L += 16) {
        const uint4* rp = (const uint4*)(featB + ((size_t)((b * HH + r0 + L) * WW + r1)) * CC) + c;
        uint4 cm0 = Z, cm1 = Z;
        // segment 0: cols [0, ew0)   — 8-wide batches, clamped idx (dup-safe)
        {
            int e = ew0 - 1;
            for (int w = 0; w < ew0; w += 8) {
                uint4 u0 = rp[(size_t)64 * w];
                uint4 u1 = rp[(size_t)64 * min(w + 1, e)];
                uint4 u2 = rp[(size_t)64 * min(w + 2, e)];
                uint4 u3 = rp[(size_t)64 * min(w + 3, e)];
                uint4 u4 = rp[(size_t)64 * min(w + 4, e)];
                uint4 u5 = rp[(size_t)64 * min(w + 5, e)];
                uint4 u6 = rp[(size_t)64 * min(w + 6, e)];
                uint4 u7 = rp[(size_t)64 * min(w + 7, e)];
                cm0 = pmax4(cm0, pmax4(pmax4(pmax4(u0,u1), pmax4(u2,u3)),
                                       pmax4(pmax4(u4,u5), pmax4(u6,u7))));
            }
        }
        // segment 1: cols [sw1, wsz)
        {
            int e = wsz - 1;
            for (int w = sw1; w < wsz; w += 8) {
                uint4 u0 = rp[(size_t)64 * w];
                uint4 u1 = rp[(size_t)64 * min(w + 1, e)];
                uint4 u2 = rp[(size_t)64 * min(w + 2, e)];
                uint4 u3 = rp[(size_t)64 * min(w + 3, e)];
                uint4 u4 = rp[(size_t)64 * min(w + 4, e)];
                uint4 u5 = rp[(size_t)64 * min(w + 5, e)];
                uint4 u6 = rp[(size_t)64 * min(w + 6, e)];
                uint4 u7 = rp[(size_t)64 * min(w + 7, e)];
                cm1 = pmax4(cm1, pmax4(pmax4(pmax4(u0,u1), pmax4(u2,u3)),
                                       pmax4(pmax4(u4,u5), pmax4(u6,u7))));
            }
        }
        if (L <  eh0) { q00 = pmax4(q00, cm0); q01 = pmax4(q01, cm1); }
        if (L >= sh1) { q10 = pmax4(q10, cm0); q11 = pmax4(q11, cm1); }
    }

    // repack: lu[g][j][c], j = jc*2 + oi (jc = channel-in-thread 0..7),
    // value = packed (oj0, oj1) for that channel.
    // component m of q covers channels (2m, 2m+1): lo/hi 16-bit lanes.
    {
        unsigned* L0 = &lu[g][0][c];
        #define REPK(mcomp, a, bq, jc0) \
            L0[((jc0)*2+0)*64]   = ((a) & 0xFFFFu) | ((bq) << 16); \
            L0[((jc0)*2+0+2)*64] = ((a) >> 16) | ((bq) & 0xFFFF0000u);
        // channels (2m): j=(2m)*2+oi ; channels (2m+1): j=(2m+1)*2+oi
        // oi=0 from (q00,q01), oi=1 from (q10,q11)
        #define REPK2(mcomp) { \
            unsigned a0 = q00.mcomp, a1 = q01.mcomp, b0 = q10.mcomp, b1 = q11.mcomp; \
            int jeven = (2*(&q00.mcomp - &q00.x)); (void)jeven; }
        // (macros got unwieldy — do it explicitly)
        #undef REPK
        #undef REPK2
        unsigned a, b2;
        a = q00.x; b2 = q01.x;
        lu[g][0*4 + 0][c] = (a & 0xFFFFu) | (b2 << 16);            // ch0, oi0
        lu[g][0*4 + 2][c] = (a >> 16)     | (b2 & 0xFFFF0000u);    // ch1, oi0
        a = q10.x; b2 = q11.x;
        lu[g][0*4 + 1][c] = (a & 0xFFFFu) | (b2 << 16);            // ch0, oi1
        lu[g][0*4 + 3][c] = (a >> 16)     | (b2 & 0xFFFF0000u);    // ch1, oi1
        a = q00.y; b2 = q01.y;
        lu[g][1*4 + 0][c] = (a & 0xFFFFu) | (b2 << 16);
        lu[g][1*4 + 2][c] = (a >> 16)     | (b2 & 0xFFFF0000u);
        a = q10.y; b2 = q11.y;
        lu[g][1*4 + 1][c] = (a & 0xFFFFu) | (b2 << 16);
        lu[g][1*4 + 3][c] = (a >> 16)     | (b2 & 0xFFFF0000u);
        a = q00.z; b2 = q01.z;
        lu[g][2*4 + 0][c] = (a & 0xFFFFu) | (b2 << 16);
        lu[g][2*4 + 2][c] = (a >> 16)     | (b2 & 0xFFFF0000u);
        a = q10.z; b2 = q11.z;
        lu[g][2*4 + 1][c] = (a & 0xFFFFu) | (b2 << 16);
        lu[g][2*4 + 3][c] = (a >> 16)     | (b2 & 0xFFFF0000u);
        a = q00.w; b2 = q01.w;
        lu[g][3*4 + 0][c] = (a & 0xFFFFu) | (b2 << 16);
        lu[g][3*4 + 2][c] = (a >> 16)     | (b2 & 0xFFFF0000u);
        a = q10.w; b2 = q11.w;
        lu[g][3*4 + 1][c] = (a & 0xFFFFu) | (b2 << 16);
        lu[g][3*4 + 3][c] = (a >> 16)     | (b2 & 0xFFFF0000u);
    }
    __syncthreads();

    // cross-rowgroup reduce + ReLU (mapped(+0)=0x8000); 4 consecutive uints/thread
    int c2 = tid & 63, j0 = (tid >> 6) * 4;
    unsigned ou[4];
    #pragma unroll
    for (int jj = 0; jj < 4; jj++) {
        int j = j0 + jj;
        unsigned m = pmax(pmax(lu[0][j][c2], lu[1][j][c2]),
                          pmax(lu[2][j][c2], lu[3][j][c2]));
        ou[jj] = pmax(m, 0x80008000u);
    }
    unsigned* dst = (unsigned*)(pp + ((size_t)(b * NR + n) * NCH + ch) * FF);
    *(uint4*)(dst + c2 * 16 + j0) = make_uint4(ou[0], ou[1], ou[2], ou[3]);
}

// NOTE on lu j-index above: j = jc*2 + oi with jc = 2m (+0) or 2m+1 (+2 in the
// *4 blocks): lu[g][m*4 + {0,1,2,3}] = {(ch 2m,oi0),(ch 2m,oi1),(ch 2m+1,oi0),(ch 2m+1,oi1)}
// i.e. j = jc*2+oi exactly. pp uint index = c*16 + j = channel*2 + oi pairs. Same
// layout k_gemm has read since R4.

// ---------------- Kernel 3: reduce chunks + unmap + BN1 + GEMM + BN2 --------
__global__ __launch_bounds__(1024) void k_gemm(const ushort* __restrict__ pp,
                                               const float* __restrict__ W1T4,
                                               const float* __restrict__ bl1,
                                               const float* __restrict__ g1,
                                               const float* __restrict__ b1,
                                               const float* __restrict__ g2,
                                               const float* __restrict__ b2,
                                               float* __restrict__ out) {
    __shared__ float xs[BB][FF];          // 32 KB
    __shared__ float pd[16][BB][OO];      // 16 KB
    __shared__ float pw[16][OO];          // 4 KB
    __shared__ float part_s[16], part_q[16];
    __shared__ float sm2[4], sq2[4];
    int n = blockIdx.x;
    int tid = threadIdx.x;

    float s_acc = 0.f, q_acc = 0.f;
    #pragma unroll
    for (int k2 = 0; k2 < 2; k2++) {
        int gi = tid + (k2 << 10);
        int bb = gi >> 9;
        int idx = gi & 511;
        const unsigned* base = (const unsigned*)(pp + ((size_t)(bb * NR + n)) * NCH * FF);
        uint2 m = *(const uint2*)(base + 0 * (FF / 2) + idx * 2);
        #pragma unroll
        for (int cch = 1; cch < NCH; cch++) {
            uint2 u = *(const uint2*)(base + cch * (FF / 2) + idx * 2);
            m.x = pmax(m.x, u.x);
            m.y = pmax(m.y, u.y);
        }
        float v0, v1, v2, v3;
        unmap2(m.x, v0, v1);
        unmap2(m.y, v2, v3);
        *(float4*)&xs[bb][idx << 2] = make_float4(v0, v1, v2, v3);
        s_acc += v0 + v1 + v2 + v3;
        q_acc += v0*v0 + v1*v1 + v2*v2 + v3*v3;
    }
    for (int off = 32; off; off >>= 1) {
        s_acc += __shfl_down(s_acc, off);
        q_acc += __shfl_down(q_acc, off);
    }
    if ((tid & 63) == 0) { part_s[tid >> 6] = s_acc; part_q[tid >> 6] = q_acc; }
    __syncthreads();
    float ts = 0.f, tq = 0.f;
    #pragma unroll
    for (int i = 0; i < 16; i++) { ts += part_s[i]; tq += part_q[i]; }
    const float inv1 = 1.f / (float)(BB * FF);
    float mean = ts * inv1;
    float var  = tq * inv1 - mean * mean;
    float a1n  = g1[n] * rsqrtf(var + EPSV);
    float c1n  = b1[n] - mean * a1n;

    int sc = tid >> 6;
    int o  = tid & 63;
    int k4a = sc << 5;
    float a0 = 0.f, a1 = 0.f, a2 = 0.f, a3 = 0.f, wsum = 0.f;
    #pragma unroll 4
    for (int k4 = k4a; k4 < k4a + 32; k4++) {
        float4 w4 = *(const float4*)(W1T4 + (size_t)k4 * 256 + o * 4);
        float4 x0 = *(const float4*)&xs[0][k4 << 2];
        float4 x1 = *(const float4*)&xs[1][k4 << 2];
        float4 x2 = *(const float4*)&xs[2][k4 << 2];
        float4 x3 = *(const float4*)&xs[3][k4 << 2];
        wsum += w4.x + w4.y + w4.z + w4.w;
        a0 += w4.x*x0.x + w4.y*x0.y + w4.z*x0.z + w4.w*x0.w;
        a1 += w4.x*x1.x + w4.y*x1.y + w4.z*x1.z + w4.w*x1.w;
        a2 += w4.x*x2.x + w4.y*x2.y + w4.z*x2.z + w4.w*x2.w;
        a3 += w4.x*x3.x + w4.y*x3.y + w4.z*x3.z + w4.w*x3.w;
    }
    pd[sc][0][o] = a0; pd[sc][1][o] = a1; pd[sc][2][o] = a2; pd[sc][3][o] = a3;
    pw[sc][o] = wsum;
    __syncthreads();

    float y = 0.f;
    int b = tid >> 6;
    if (tid < 256) {
        float dot = 0.f, wsm = 0.f;
        #pragma unroll
        for (int ss = 0; ss < 16; ss++) { dot += pd[ss][b][o]; wsm += pw[ss][o]; }
        y = a1n * dot + c1n * wsm + bl1[o];
        float rs = y, rq = y * y;
        for (int off = 32; off; off >>= 1) {
            rs += __shfl_down(rs, off);
            rq += __shfl_down(rq, off);
        }
        if (o == 0) { sm2[b] = rs; sq2[b] = rq; }
    }
    __syncthreads();
    if (tid < 256) {
        float sm  = sm2[0] + sm2[1] + sm2[2] + sm2[3];
        float sqm = sq2[0] + sq2[1] + sq2[2] + sq2[3];
        const float inv2 = 1.f / 256.f;
        float mean2 = sm * inv2;
        float var2  = sqm * inv2 - mean2 * mean2;
        float r2s = rsqrtf(var2 + EPSV);
        out[((size_t)b * NR + n) * OO + o] = (y - mean2) * r2s * g2[n] + b2[n];
    }
}

extern "C" void kernel_launch(void* const* d_in, const int* in_sizes, int n_in,
                              void* d_out, int out_size, void* d_ws, size_t ws_size,
                              hipStream_t stream) {
    const float* feat = (const float*)d_in[0];
    const float* rois = (const float*)d_in[1];
    const float* g1   = (const float*)d_in[2];
    const float* b1   = (const float*)d_in[3];
    const float* W1   = (const float*)d_in[4];
    const float* bl1  = (const float*)d_in[5];
    const float* g2   = (const float*)d_in[6];
    const float* b2   = (const float*)d_in[7];
    float* out = (float*)d_out;

    ushort* featB = (ushort*)d_ws;                    // mapped u16
    float*  W1T4  = (float*)(featB + (size_t)BB*HH*WW*CC);
    ushort* pp    = (ushort*)(W1T4 + (size_t)OO*FF);  // mapped u16

    k_prep<<<dim3(72, 16, 5), 256, 0, stream>>>(feat, W1, featB, W1T4);
    k_pool<<<dim3(NCH, BB * NR), 256, 0, stream>>>(featB, rois, pp);
    k_gemm<<<NR, 1024, 0, stream>>>(pp, W1T4, bl1, g1, b1, g2, b2, out);
}